// Round 1
// baseline (46.106 us; speedup 1.0000x reference)
//
#include <hip/hip_runtime.h>
#include <hip/hip_bf16.h>

// CXLMultiHeadEmbedding: out[r, :] = table[ids[r] + (r % H) * N_PER_HEAD, :]
// r = (b*L + l)*H + h, D = 64 floats per row.
//
// Pure memory-bound gather. 16 threads per row, one float4 (16 B) each:
// coalesced 256 B per 16-lane group on both the table read and the out write.

constexpr int   H_HEADS    = 8;
constexpr int   D_DIM      = 64;          // floats per row
constexpr long long N_PER  = 100000;      // rows per head segment (all equal)

__global__ __launch_bounds__(256) void
cxl_embed_gather(const int* __restrict__ ids,
                 const float* __restrict__ table,
                 float* __restrict__ out,
                 long long n_rows)
{
    // Each logical work item i handles float4 #(i & 15) of row (i >> 4).
    const long long total  = n_rows * (D_DIM / 4 / 4);   // n_rows * 16... see below
    // D=64 floats = 16 float4 chunks per row
    const long long nchunk = n_rows * 16;
    (void)total;

    long long tid    = (long long)blockIdx.x * blockDim.x + threadIdx.x;
    long long stride = (long long)gridDim.x * blockDim.x;

    for (long long i = tid; i < nchunk; i += stride) {
        long long r = i >> 4;          // row index
        int       q = (int)(i & 15);   // float4 chunk within row
        int       h = (int)(r & (H_HEADS - 1));   // r % 8 (H=8, innermost dim)

        long long idx = (long long)ids[r] + (long long)h * N_PER;

        const float4* __restrict__ src =
            reinterpret_cast<const float4*>(table + idx * D_DIM);
        float4* __restrict__ dst =
            reinterpret_cast<float4*>(out + r * D_DIM);

        dst[q] = src[q];
    }
}

extern "C" void kernel_launch(void* const* d_in, const int* in_sizes, int n_in,
                              void* d_out, int out_size, void* d_ws, size_t ws_size,
                              hipStream_t stream)
{
    const int*   ids   = (const int*)d_in[0];     // [B, L, H] int32
    const float* table = (const float*)d_in[1];   // [TOTAL_N, D] fp32
    float*       out   = (float*)d_out;           // [B, L, H, D] fp32

    const long long n_rows = (long long)in_sizes[0];   // B*L*H = 524288

    const int block = 256;
    const int grid  = 2048;   // grid-stride; 2048 blocks saturates 256 CUs

    cxl_embed_gather<<<grid, block, 0, stream>>>(ids, table, out, n_rows);
}

// Round 3
// 45.102 us; speedup vs baseline: 1.0223x; 1.0223x over previous
//
#include <hip/hip_runtime.h>
#include <hip/hip_bf16.h>

// CXLMultiHeadEmbedding: out[r, :] = table[ids[r] + (r % H) * N_PER_HEAD, :]
// r = (b*L + l)*H + h, D = 64 floats per row.
//
// Memory-bound gather. 16 threads per row, one 16 B vector each:
// coalesced 256 B per 16-lane group on table read and out write.
// Output stores are NON-TEMPORAL (nt flag) so the 134 MB of streaming
// writes don't evict the 205 MB table from the 256 MiB Infinity Cache —
// gather reads should then be L3 hits on timed replays.

constexpr int       H_HEADS = 8;
constexpr int       D_DIM   = 64;        // floats per row
constexpr long long N_PER   = 100000;    // rows per head segment (all equal)

typedef float f32x4 __attribute__((ext_vector_type(4)));

__global__ __launch_bounds__(256) void
cxl_embed_gather(const int* __restrict__ ids,
                 const float* __restrict__ table,
                 float* __restrict__ out,
                 long long n_rows)
{
    // D=64 floats = 16 16B chunks per row
    const long long nchunk = n_rows * 16;

    long long tid    = (long long)blockIdx.x * blockDim.x + threadIdx.x;
    long long stride = (long long)gridDim.x * blockDim.x;

    for (long long i = tid; i < nchunk; i += stride) {
        long long r = i >> 4;                   // row index
        int       q = (int)(i & 15);            // 16B chunk within row
        int       h = (int)(r & (H_HEADS - 1)); // r % 8 (H innermost dim)

        long long idx = (long long)ids[r] + (long long)h * N_PER;

        const f32x4* __restrict__ src =
            reinterpret_cast<const f32x4*>(table + idx * D_DIM);
        f32x4* __restrict__ dst =
            reinterpret_cast<f32x4*>(out + r * D_DIM);

        f32x4 v = src[q];
        __builtin_nontemporal_store(v, dst + q);
    }
}

extern "C" void kernel_launch(void* const* d_in, const int* in_sizes, int n_in,
                              void* d_out, int out_size, void* d_ws, size_t ws_size,
                              hipStream_t stream)
{
    const int*   ids   = (const int*)d_in[0];     // [B, L, H] int32
    const float* table = (const float*)d_in[1];   // [TOTAL_N, D] fp32
    float*       out   = (float*)d_out;           // [B, L, H, D] fp32

    const long long n_rows = (long long)in_sizes[0];   // B*L*H = 524288

    const int block = 256;
    const int grid  = 2048;   // grid-stride; saturates 256 CUs

    cxl_embed_gather<<<grid, block, 0, stream>>>(ids, table, out, n_rows);
}

// Round 4
// 43.732 us; speedup vs baseline: 1.0543x; 1.0313x over previous
//
#include <hip/hip_runtime.h>
#include <hip/hip_bf16.h>

// CXLMultiHeadEmbedding: out[r, :] = table[ids[r] + (r % H) * N_PER_HEAD, :]
// r = (b*L + l)*H + h, D = 64 floats per row.
//
// Memory-bound random gather. One 16 B chunk per THREAD (no grid-stride
// loop): 16 threads cover one 256 B row; coalesced on both sides.
// Max TLP variant — each wave issues 4 row-gathers + stores and retires,
// so there is no loop-carried serialization; the scheduler keeps ~8 waves
// per SIMD in flight.
//
// HBM floor per call: 134 MB out-write + ~98 MB unique table rows + 2 MB
// ids ≈ 234 MB → 37 µs @ 6.3 TB/s. The harness's 819 MB fills between
// replays evict L3, so table reads are cold each call (L3-residency
// across calls is impossible).

constexpr int       H_HEADS = 8;
constexpr int       D_DIM   = 64;        // floats per row
constexpr long long N_PER   = 100000;    // rows per head segment (all equal)

typedef float f32x4 __attribute__((ext_vector_type(4)));

__global__ __launch_bounds__(256) void
cxl_embed_gather(const int* __restrict__ ids,
                 const float* __restrict__ table,
                 float* __restrict__ out,
                 long long nchunk)
{
    long long i = (long long)blockIdx.x * blockDim.x + threadIdx.x;
    if (i >= nchunk) return;

    long long r = i >> 4;                   // row index
    int       q = (int)(i & 15);            // 16B chunk within row
    int       h = (int)(r & (H_HEADS - 1)); // r % 8 (H innermost dim)

    long long idx = (long long)ids[r] + (long long)h * N_PER;

    const f32x4* __restrict__ src =
        reinterpret_cast<const f32x4*>(table + idx * D_DIM);
    f32x4* __restrict__ dst =
        reinterpret_cast<f32x4*>(out + r * D_DIM);

    f32x4 v = src[q];
    __builtin_nontemporal_store(v, dst + q);
}

extern "C" void kernel_launch(void* const* d_in, const int* in_sizes, int n_in,
                              void* d_out, int out_size, void* d_ws, size_t ws_size,
                              hipStream_t stream)
{
    const int*   ids   = (const int*)d_in[0];     // [B, L, H] int32
    const float* table = (const float*)d_in[1];   // [TOTAL_N, D] fp32
    float*       out   = (float*)d_out;           // [B, L, H, D] fp32

    const long long n_rows = (long long)in_sizes[0];   // B*L*H = 524288
    const long long nchunk = n_rows * 16;              // 16B chunks

    const int block = 256;
    const int grid  = (int)((nchunk + block - 1) / block);   // 32768

    cxl_embed_gather<<<grid, block, 0, stream>>>(ids, table, out, nchunk);
}